// Round 1
// baseline (17742.703 us; speedup 1.0000x reference)
//
#include <hip/hip_runtime.h>

// LSTM autoencoder, MI355X. Round 1: per-step fp16-MFMA kernels.
// B=128,S=512,D=128,H=1024. Decoder y-feedback folded into combined weight
// W2 = dec_Whh + dec_Wih[:,:D]@out_W, so recurrence is a single GEMM/step.
// h double-buffered (fp16) across step kernels; c fp32 partitioned (no races).

#define BB 128
#define SS 512
#define DD 128
#define HH 1024
#define G4 4096
#define KENC 1152

typedef _Float16 half8 __attribute__((ext_vector_type(8)));
typedef float floatx4 __attribute__((ext_vector_type(4)));

__device__ __forceinline__ float sigf(float x) { return 1.0f / (1.0f + __expf(-x)); }
__device__ __forceinline__ float tanhfast(float x) { return 1.0f - 2.0f / (1.0f + __expf(2.0f * x)); }

// ---- prep kernels -----------------------------------------------------------

__global__ void k_prep_encw(const float* __restrict__ eWih, const float* __restrict__ eWhh,
                            _Float16* __restrict__ encW) {
  int r = blockIdx.x;  // 0..4095
  for (int k = threadIdx.x; k < KENC; k += blockDim.x) {
    float v = (k < DD) ? eWih[(size_t)r * DD + k] : eWhh[(size_t)r * HH + (k - DD)];
    encW[(size_t)r * KENC + k] = (_Float16)v;
  }
}

__global__ void k_prep_simple(const float* __restrict__ dWih, const float* __restrict__ dWhh,
                              const float* __restrict__ oW,
                              const float* __restrict__ eBih, const float* __restrict__ eBhh,
                              const float* __restrict__ dBih, const float* __restrict__ dBhh,
                              const float* __restrict__ oB,
                              _Float16* __restrict__ decW1, _Float16* __restrict__ outW16,
                              float* __restrict__ encB, float* __restrict__ decB1,
                              float* __restrict__ decB2,
                              _Float16* __restrict__ hA, float* __restrict__ cbuf,
                              float* __restrict__ lossAcc) {
  int tid = blockIdx.x * blockDim.x + threadIdx.x;
  int nt = gridDim.x * blockDim.x;
  for (size_t i = tid; i < (size_t)G4 * HH; i += nt)
    decW1[i] = (_Float16)(dWih[i] + dWhh[i]);   // dec step1: inp==h_n -> Wih+Whh
  for (size_t i = tid; i < (size_t)DD * HH; i += nt)
    outW16[i] = (_Float16)oW[i];
  for (size_t i = tid; i < (size_t)BB * HH; i += nt) {
    cbuf[i] = 0.0f;
    hA[i] = (_Float16)0.0f;
  }
  if (tid == 0) lossAcc[0] = 0.0f;
  if (tid < G4) {
    encB[tid] = eBih[tid] + eBhh[tid];
    float b1 = dBih[tid] + dBhh[tid];
    decB1[tid] = b1;
    float acc = b1;  // b2 = b1 + dec_Wih[:,:D] @ out_b
    for (int j = 0; j < DD; ++j) acc += dWih[(size_t)tid * HH + j] * oB[j];
    decB2[tid] = acc;
  }
}

// W2 = dec_Whh + dec_Wih[:,:D] @ out_W   (4096 x 1024)
__global__ void k_prep_decw2(const float* __restrict__ dWih, const float* __restrict__ dWhh,
                             const float* __restrict__ oW, _Float16* __restrict__ decW2) {
  int r = blockIdx.x >> 2;                       // 0..4095
  int c = ((blockIdx.x & 3) << 8) + threadIdx.x; // 0..1023
  float acc = dWhh[(size_t)r * HH + c];
  for (int j = 0; j < DD; ++j) acc += dWih[(size_t)r * HH + j] * oW[(size_t)j * HH + c];
  decW2[(size_t)r * HH + c] = (_Float16)acc;
}

// ---- step kernels -----------------------------------------------------------
// Grid 512 x 64 threads (1 wave). blockIdx: ut = &63 (unit tile, keys XCD via %8
// so same-W blocks share an L2), mt = >>6 (batch tile). Wave computes the 16x16
// i/f/g/o tiles for (16 rows x 16 hidden units), full K, then the cell update.
// MFMA 16x16x32_f16 layouts (verified on gfx950):
//   A: m=lane&15, k=(lane>>4)*8+j ; B: n=lane&15, k=(lane>>4)*8+j
//   C/D: row=(lane>>4)*4+reg, col=lane&15

__global__ __launch_bounds__(64) void k_enc_step(
    const float* __restrict__ x, const _Float16* __restrict__ W,
    const float* __restrict__ bias, const _Float16* __restrict__ hin,
    _Float16* __restrict__ hout, float* __restrict__ cbuf,
    float* __restrict__ encOut, int t) {
  int lane = threadIdx.x;
  int ut = blockIdx.x & 63, mt = blockIdx.x >> 6;
  int n = lane & 15, q = lane >> 4;
  int m0 = mt << 4, u0 = ut << 4;
  floatx4 acc0 = {0,0,0,0}, acc1 = {0,0,0,0}, acc2 = {0,0,0,0}, acc3 = {0,0,0,0};
  const _Float16* w0 = W + (size_t)(0 * HH + u0 + n) * KENC;
  const _Float16* w1 = W + (size_t)(1 * HH + u0 + n) * KENC;
  const _Float16* w2 = W + (size_t)(2 * HH + u0 + n) * KENC;
  const _Float16* w3 = W + (size_t)(3 * HH + u0 + n) * KENC;
  const float* xrow = x + (size_t)(m0 + n) * (SS * DD) + (size_t)t * DD;
  const _Float16* hrow = hin + (size_t)(m0 + n) * HH;
  for (int kI = 0; kI < 36; ++kI) {   // K = 128 (x) + 1024 (h)
    int k0 = kI * 32 + q * 8;
    half8 a;
    if (kI < 4) {
#pragma unroll
      for (int j = 0; j < 8; ++j) a[j] = (_Float16)xrow[k0 + j];
    } else {
      a = *(const half8*)(hrow + (k0 - DD));
    }
    acc0 = __builtin_amdgcn_mfma_f32_16x16x32_f16(a, *(const half8*)(w0 + k0), acc0, 0, 0, 0);
    acc1 = __builtin_amdgcn_mfma_f32_16x16x32_f16(a, *(const half8*)(w1 + k0), acc1, 0, 0, 0);
    acc2 = __builtin_amdgcn_mfma_f32_16x16x32_f16(a, *(const half8*)(w2 + k0), acc2, 0, 0, 0);
    acc3 = __builtin_amdgcn_mfma_f32_16x16x32_f16(a, *(const half8*)(w3 + k0), acc3, 0, 0, 0);
  }
  int u = u0 + n;
  float bi = bias[u], bf = bias[HH + u], bg = bias[2 * HH + u], bo = bias[3 * HH + u];
#pragma unroll
  for (int r = 0; r < 4; ++r) {
    int m = m0 + q * 4 + r;
    float gi = sigf(acc0[r] + bi);
    float gf = sigf(acc1[r] + bf);
    float gg = tanhfast(acc2[r] + bg);
    float go = sigf(acc3[r] + bo);
    size_t idx = (size_t)m * HH + u;
    float cv = gf * cbuf[idx] + gi * gg;
    cbuf[idx] = cv;
    float hv = go * tanhfast(cv);
    hout[idx] = (_Float16)hv;
    encOut[(size_t)m * (SS * HH) + (size_t)t * HH + u] = hv;  // encoded output (fp32)
  }
}

__global__ __launch_bounds__(64) void k_dec_step(
    const _Float16* __restrict__ W, const float* __restrict__ bias,
    const _Float16* __restrict__ hin, _Float16* __restrict__ hout,
    float* __restrict__ cbuf, const _Float16* __restrict__ outW,
    const float* __restrict__ oB, const float* __restrict__ x,
    float* __restrict__ recon, float* __restrict__ lossAcc, int s) {
  int lane = threadIdx.x;
  int ut = blockIdx.x & 63, mt = blockIdx.x >> 6;
  int n = lane & 15, q = lane >> 4;
  int m0 = mt << 4, u0 = ut << 4;
  bool doY = (s >= 2) && (ut < 8);   // compute y_{s-1} = h_{s-1} @ out_W.T (+loss) here
  floatx4 acc0 = {0,0,0,0}, acc1 = {0,0,0,0}, acc2 = {0,0,0,0}, acc3 = {0,0,0,0};
  floatx4 accY = {0,0,0,0};
  const _Float16* w0 = W + (size_t)(0 * HH + u0 + n) * HH;
  const _Float16* w1 = W + (size_t)(1 * HH + u0 + n) * HH;
  const _Float16* w2 = W + (size_t)(2 * HH + u0 + n) * HH;
  const _Float16* w3 = W + (size_t)(3 * HH + u0 + n) * HH;
  const _Float16* hrow = hin + (size_t)(m0 + n) * HH;
  const _Float16* orow = outW + (size_t)(u0 + n) * HH;  // only used when ut<8
  for (int kI = 0; kI < 32; ++kI) {   // K = 1024
    int k0 = kI * 32 + q * 8;
    half8 a = *(const half8*)(hrow + k0);
    acc0 = __builtin_amdgcn_mfma_f32_16x16x32_f16(a, *(const half8*)(w0 + k0), acc0, 0, 0, 0);
    acc1 = __builtin_amdgcn_mfma_f32_16x16x32_f16(a, *(const half8*)(w1 + k0), acc1, 0, 0, 0);
    acc2 = __builtin_amdgcn_mfma_f32_16x16x32_f16(a, *(const half8*)(w2 + k0), acc2, 0, 0, 0);
    acc3 = __builtin_amdgcn_mfma_f32_16x16x32_f16(a, *(const half8*)(w3 + k0), acc3, 0, 0, 0);
    if (doY)
      accY = __builtin_amdgcn_mfma_f32_16x16x32_f16(a, *(const half8*)(orow + k0), accY, 0, 0, 0);
  }
  int u = u0 + n;
  float bi = bias[u], bf = bias[HH + u], bg = bias[2 * HH + u], bo = bias[3 * HH + u];
#pragma unroll
  for (int r = 0; r < 4; ++r) {
    int m = m0 + q * 4 + r;
    float gi = sigf(acc0[r] + bi);
    float gf = sigf(acc1[r] + bf);
    float gg = tanhfast(acc2[r] + bg);
    float go = sigf(acc3[r] + bo);
    size_t idx = (size_t)m * HH + u;
    float cv = gf * cbuf[idx] + gi * gg;
    cbuf[idx] = cv;
    float hv = go * tanhfast(cv);
    hout[idx] = (_Float16)hv;
  }
  if (doY) {
    int d = u0 + n;            // ut<8 -> d in [0,128)
    int ty = s - 2;            // y_{s-1} -> recon time index s-2
    float ob = oB[d];
    float ls = 0.0f;
#pragma unroll
    for (int r = 0; r < 4; ++r) {
      int m = m0 + q * 4 + r;
      float yv = accY[r] + ob;
      size_t ix = (size_t)m * (SS * DD) + (size_t)ty * DD + d;
      recon[ix] = yv;
      float e = yv - x[ix];
      ls += e * e;
    }
    for (int off = 32; off; off >>= 1) ls += __shfl_xor(ls, off, 64);
    if (lane == 0) atomicAdd(lossAcc, ls);
  }
}

__global__ __launch_bounds__(64) void k_y_final(
    const _Float16* __restrict__ hin, const _Float16* __restrict__ outW,
    const float* __restrict__ oB, const float* __restrict__ x,
    float* __restrict__ recon, float* __restrict__ lossAcc) {
  int lane = threadIdx.x;
  int mt = blockIdx.x >> 3, dt = blockIdx.x & 7;
  int n = lane & 15, q = lane >> 4;
  int m0 = mt << 4, d0 = dt << 4;
  floatx4 acc = {0,0,0,0};
  const _Float16* hrow = hin + (size_t)(m0 + n) * HH;
  const _Float16* orow = outW + (size_t)(d0 + n) * HH;
  for (int kI = 0; kI < 32; ++kI) {
    int k0 = kI * 32 + q * 8;
    acc = __builtin_amdgcn_mfma_f32_16x16x32_f16(*(const half8*)(hrow + k0),
                                                 *(const half8*)(orow + k0), acc, 0, 0, 0);
  }
  int d = d0 + n;
  float ob = oB[d];
  float ls = 0.0f;
#pragma unroll
  for (int r = 0; r < 4; ++r) {
    int m = m0 + q * 4 + r;
    float yv = acc[r] + ob;
    size_t ix = (size_t)m * (SS * DD) + (size_t)511 * DD + d;
    recon[ix] = yv;
    float e = yv - x[ix];
    ls += e * e;
  }
  for (int off = 32; off; off >>= 1) ls += __shfl_xor(ls, off, 64);
  if (lane == 0) atomicAdd(lossAcc, ls);
}

__global__ void k_finalize(const float* __restrict__ lossAcc, float* __restrict__ lossOut) {
  lossOut[0] = lossAcc[0] * (1.0f / (float)BB);
}

// ---- host -------------------------------------------------------------------

extern "C" void kernel_launch(void* const* d_in, const int* in_sizes, int n_in,
                              void* d_out, int out_size, void* d_ws, size_t ws_size,
                              hipStream_t stream) {
  const float* x    = (const float*)d_in[0];
  const float* eWih = (const float*)d_in[1];
  const float* eWhh = (const float*)d_in[2];
  const float* eBih = (const float*)d_in[3];
  const float* eBhh = (const float*)d_in[4];
  const float* dWih = (const float*)d_in[5];
  const float* dWhh = (const float*)d_in[6];
  const float* dBih = (const float*)d_in[7];
  const float* dBhh = (const float*)d_in[8];
  const float* oW   = (const float*)d_in[9];
  const float* oB   = (const float*)d_in[10];

  float* out = (float*)d_out;
  float* recon = out;                                   // (B,S,D)
  float* encOut = out + (size_t)BB * SS * DD;           // (B,S,H)
  float* lossOut = out + (size_t)BB * SS * DD + (size_t)BB * SS * HH;  // scalar

  char* p = (char*)d_ws;
  auto alloc = [&](size_t bytes) {
    char* r = p;
    p += (bytes + 255) & ~(size_t)255;
    return r;
  };
  _Float16* encW   = (_Float16*)alloc((size_t)G4 * KENC * 2);  // [Wih|Whh] fp16
  _Float16* decW1  = (_Float16*)alloc((size_t)G4 * HH * 2);
  _Float16* decW2  = (_Float16*)alloc((size_t)G4 * HH * 2);
  _Float16* outW16 = (_Float16*)alloc((size_t)DD * HH * 2);
  float* encB  = (float*)alloc((size_t)G4 * 4);
  float* decB1 = (float*)alloc((size_t)G4 * 4);
  float* decB2 = (float*)alloc((size_t)G4 * 4);
  _Float16* hA = (_Float16*)alloc((size_t)BB * HH * 2);
  _Float16* hB = (_Float16*)alloc((size_t)BB * HH * 2);
  float* cbuf = (float*)alloc((size_t)BB * HH * 4);
  float* lossAcc = (float*)alloc(256);
  (void)in_sizes; (void)n_in; (void)out_size; (void)ws_size;

  k_prep_encw<<<G4, 256, 0, stream>>>(eWih, eWhh, encW);
  k_prep_simple<<<2048, 256, 0, stream>>>(dWih, dWhh, oW, eBih, eBhh, dBih, dBhh, oB,
                                          decW1, outW16, encB, decB1, decB2, hA, cbuf, lossAcc);
  k_prep_decw2<<<G4 * 4, 256, 0, stream>>>(dWih, dWhh, oW, decW2);

  _Float16* hin = hA;
  _Float16* hout = hB;
  for (int t = 0; t < SS; ++t) {
    k_enc_step<<<512, 64, 0, stream>>>(x, encW, encB, hin, hout, cbuf, encOut, t);
    _Float16* tmp = hin; hin = hout; hout = tmp;
  }
  for (int s = 1; s <= SS; ++s) {
    const _Float16* W = (s == 1) ? decW1 : decW2;
    const float* bias = (s == 1) ? decB1 : decB2;
    k_dec_step<<<512, 64, 0, stream>>>(W, bias, hin, hout, cbuf, outW16, oB, x,
                                       recon, lossAcc, s);
    _Float16* tmp = hin; hin = hout; hout = tmp;
  }
  k_y_final<<<64, 64, 0, stream>>>(hin, outW16, oB, x, recon, lossAcc);
  k_finalize<<<1, 1, 0, stream>>>(lossAcc, lossOut);
}

// Round 2
// 12188.237 us; speedup vs baseline: 1.4557x; 1.4557x over previous
//
#include <hip/hip_runtime.h>

// LSTM autoencoder, MI355X. Round 2: per-step kernels with 8-wave K-split.
// 256 blocks x 512 threads (8 waves/CU): block = 32 batch rows x 16 units x 4
// gates; waves split K (128 each), partials reduced via 2-level LDS tree.
// Weight L2 amplification 4x (was 8x). Decoder y-feedback stays folded into
// W2 = dec_Whh + dec_Wih[:,:D]@out_W; y_{s-1} computed in-step (ut<8 blocks).

#define BB 128
#define SS 512
#define DD 128
#define HH 1024
#define G4 4096
#define KENC 1152

typedef _Float16 half8 __attribute__((ext_vector_type(8)));
typedef float floatx4 __attribute__((ext_vector_type(4)));

__device__ __forceinline__ float sigf(float x) { return 1.0f / (1.0f + __expf(-x)); }
__device__ __forceinline__ float tanhfast(float x) { return 1.0f - 2.0f / (1.0f + __expf(2.0f * x)); }

#define MFMA16(a, b, c) __builtin_amdgcn_mfma_f32_16x16x32_f16((a), (b), (c), 0, 0, 0)

// ---- prep kernels -----------------------------------------------------------

__global__ void k_prep_encw(const float* __restrict__ eWih, const float* __restrict__ eWhh,
                            _Float16* __restrict__ encW) {
  int r = blockIdx.x;  // 0..4095
  for (int k = threadIdx.x; k < KENC; k += blockDim.x) {
    float v = (k < DD) ? eWih[(size_t)r * DD + k] : eWhh[(size_t)r * HH + (k - DD)];
    encW[(size_t)r * KENC + k] = (_Float16)v;
  }
}

__global__ void k_prep_simple(const float* __restrict__ dWih, const float* __restrict__ dWhh,
                              const float* __restrict__ oW,
                              const float* __restrict__ eBih, const float* __restrict__ eBhh,
                              const float* __restrict__ dBih, const float* __restrict__ dBhh,
                              const float* __restrict__ oB,
                              _Float16* __restrict__ decW1, _Float16* __restrict__ outW16,
                              float* __restrict__ encB, float* __restrict__ decB1,
                              float* __restrict__ decB2,
                              _Float16* __restrict__ hA, float* __restrict__ cbuf,
                              float* __restrict__ lossAcc) {
  int tid = blockIdx.x * blockDim.x + threadIdx.x;
  int nt = gridDim.x * blockDim.x;
  for (size_t i = tid; i < (size_t)G4 * HH; i += nt)
    decW1[i] = (_Float16)(dWih[i] + dWhh[i]);   // dec step1: inp==h_n -> Wih+Whh
  for (size_t i = tid; i < (size_t)DD * HH; i += nt)
    outW16[i] = (_Float16)oW[i];
  for (size_t i = tid; i < (size_t)BB * HH; i += nt) {
    cbuf[i] = 0.0f;
    hA[i] = (_Float16)0.0f;
  }
  if (tid == 0) lossAcc[0] = 0.0f;
  if (tid < G4) {
    encB[tid] = eBih[tid] + eBhh[tid];
    float b1 = dBih[tid] + dBhh[tid];
    decB1[tid] = b1;
    float acc = b1;  // b2 = b1 + dec_Wih[:,:D] @ out_b
    for (int j = 0; j < DD; ++j) acc += dWih[(size_t)tid * HH + j] * oB[j];
    decB2[tid] = acc;
  }
}

// W2 = dec_Whh + dec_Wih[:,:D] @ out_W   (4096 x 1024)
__global__ void k_prep_decw2(const float* __restrict__ dWih, const float* __restrict__ dWhh,
                             const float* __restrict__ oW, _Float16* __restrict__ decW2) {
  int r = blockIdx.x >> 2;                       // 0..4095
  int c = ((blockIdx.x & 3) << 8) + threadIdx.x; // 0..1023
  float acc = dWhh[(size_t)r * HH + c];
  for (int j = 0; j < DD; ++j) acc += dWih[(size_t)r * HH + j] * oW[(size_t)j * HH + c];
  decW2[(size_t)r * HH + c] = (_Float16)acc;
}

// ---- step kernels -----------------------------------------------------------
// Grid 256 = (mtb 0..3)<<6 | (ut 0..63); 512 threads = 8 waves (K-split).
// ut varies fastest -> blockIdx%8 = ut%8 keys XCD; same-ut blocks share L2 slice.
// MFMA 16x16x32_f16: A[m=lane&15][k=(lane>>4)*8+j], B[n=lane&15][k=...],
// C/D: row=(lane>>4)*4+reg, col=lane&15.

__global__ __launch_bounds__(512) void k_enc_step(
    const float* __restrict__ x, const _Float16* __restrict__ W,
    const float* __restrict__ bias, const _Float16* __restrict__ hin,
    _Float16* __restrict__ hout, float* __restrict__ cbuf,
    float* __restrict__ encOut, int t) {
  __shared__ float pl[4][4][2][16][16];   // [slot][gate][mtile][row][col] 32 KB
  __shared__ float red[4][2][16][16];     // 8 KB
  int tid = threadIdx.x;
  int lane = tid & 63, w = tid >> 6;
  int n = lane & 15, q = lane >> 4;
  int ut = blockIdx.x & 63, mtb = blockIdx.x >> 6;
  int m0 = mtb << 5, u0 = ut << 4;

  floatx4 acc[4][2];
#pragma unroll
  for (int g = 0; g < 4; ++g)
#pragma unroll
    for (int mt = 0; mt < 2; ++mt) acc[g][mt] = (floatx4){0, 0, 0, 0};

  const _Float16* wr0 = W + (size_t)(0 * HH + u0 + n) * KENC + q * 8;
  const _Float16* wr1 = W + (size_t)(1 * HH + u0 + n) * KENC + q * 8;
  const _Float16* wr2 = W + (size_t)(2 * HH + u0 + n) * KENC + q * 8;
  const _Float16* wr3 = W + (size_t)(3 * HH + u0 + n) * KENC + q * 8;

  int kh0 = w << 7;   // this wave's 128-wide K slice of the h part
  const _Float16* h0 = hin + (size_t)(m0 + n) * HH + kh0 + q * 8;
  const _Float16* h1 = h0 + (size_t)16 * HH;
#pragma unroll
  for (int kk = 0; kk < 4; ++kk) {
    int ko = kk * 32;
    half8 a0 = *(const half8*)(h0 + ko);
    half8 a1 = *(const half8*)(h1 + ko);
    int wk = DD + kh0 + ko;
    half8 b0 = *(const half8*)(wr0 + wk);
    half8 b1 = *(const half8*)(wr1 + wk);
    half8 b2 = *(const half8*)(wr2 + wk);
    half8 b3 = *(const half8*)(wr3 + wk);
    acc[0][0] = MFMA16(a0, b0, acc[0][0]); acc[0][1] = MFMA16(a1, b0, acc[0][1]);
    acc[1][0] = MFMA16(a0, b1, acc[1][0]); acc[1][1] = MFMA16(a1, b1, acc[1][1]);
    acc[2][0] = MFMA16(a0, b2, acc[2][0]); acc[2][1] = MFMA16(a1, b2, acc[2][1]);
    acc[3][0] = MFMA16(a0, b3, acc[3][0]); acc[3][1] = MFMA16(a1, b3, acc[3][1]);
  }
  if (w < 4) {  // waves 0..3 take the x part (K=128, 32 each)
    int xk = w << 5;
    const float* xr0 = x + (size_t)(m0 + n) * (SS * DD) + (size_t)t * DD + xk + q * 8;
    const float* xr1 = xr0 + (size_t)16 * (SS * DD);
    floatx4 p0 = *(const floatx4*)xr0;
    floatx4 p1 = *(const floatx4*)(xr0 + 4);
    floatx4 p2 = *(const floatx4*)xr1;
    floatx4 p3 = *(const floatx4*)(xr1 + 4);
    half8 a0, a1;
#pragma unroll
    for (int j = 0; j < 4; ++j) {
      a0[j] = (_Float16)p0[j]; a0[j + 4] = (_Float16)p1[j];
      a1[j] = (_Float16)p2[j]; a1[j + 4] = (_Float16)p3[j];
    }
    half8 b0 = *(const half8*)(wr0 + xk);
    half8 b1 = *(const half8*)(wr1 + xk);
    half8 b2 = *(const half8*)(wr2 + xk);
    half8 b3 = *(const half8*)(wr3 + xk);
    acc[0][0] = MFMA16(a0, b0, acc[0][0]); acc[0][1] = MFMA16(a1, b0, acc[0][1]);
    acc[1][0] = MFMA16(a0, b1, acc[1][0]); acc[1][1] = MFMA16(a1, b1, acc[1][1]);
    acc[2][0] = MFMA16(a0, b2, acc[2][0]); acc[2][1] = MFMA16(a1, b2, acc[2][1]);
    acc[3][0] = MFMA16(a0, b3, acc[3][0]); acc[3][1] = MFMA16(a1, b3, acc[3][1]);
  }

  // 2-level reduction tree over the 8 K-slices
  if (w >= 4) {
#pragma unroll
    for (int g = 0; g < 4; ++g)
#pragma unroll
      for (int mt = 0; mt < 2; ++mt)
#pragma unroll
        for (int r = 0; r < 4; ++r)
          pl[w - 4][g][mt][q * 4 + r][n] = acc[g][mt][r];
  }
  __syncthreads();
  if (w < 4) {
#pragma unroll
    for (int g = 0; g < 4; ++g)
#pragma unroll
      for (int mt = 0; mt < 2; ++mt)
#pragma unroll
        for (int r = 0; r < 4; ++r)
          acc[g][mt][r] += pl[w][g][mt][q * 4 + r][n];
#pragma unroll
    for (int g = 0; g < 4; ++g)
#pragma unroll
      for (int mt = 0; mt < 2; ++mt)
#pragma unroll
        for (int r = 0; r < 4; ++r)
          pl[w][g][mt][q * 4 + r][n] = acc[g][mt][r];
  }
  __syncthreads();
  {  // final 4-way reduce: 2048 sums, 4 per thread (vectorized)
    int base = tid * 4;
    int col = base & 15, row = (base >> 4) & 15, mt = (base >> 8) & 1, g = base >> 9;
    floatx4 s = *(const floatx4*)&pl[0][g][mt][row][col];
    s += *(const floatx4*)&pl[1][g][mt][row][col];
    s += *(const floatx4*)&pl[2][g][mt][row][col];
    s += *(const floatx4*)&pl[3][g][mt][row][col];
    *(floatx4*)&red[g][mt][row][col] = s;
  }
  __syncthreads();
  {  // cell update: thread t -> (m_local = t>>4, u_local = t&15)
    int m_l = tid >> 4, u_l = tid & 15;
    int mt = m_l >> 4, row = m_l & 15;
    int u = u0 + u_l, m = m0 + m_l;
    float gi = sigf(red[0][mt][row][u_l] + bias[u]);
    float gf = sigf(red[1][mt][row][u_l] + bias[HH + u]);
    float gg = tanhfast(red[2][mt][row][u_l] + bias[2 * HH + u]);
    float go = sigf(red[3][mt][row][u_l] + bias[3 * HH + u]);
    size_t idx = (size_t)m * HH + u;
    float cv = gf * cbuf[idx] + gi * gg;
    cbuf[idx] = cv;
    float hv = go * tanhfast(cv);
    hout[idx] = (_Float16)hv;
    encOut[(size_t)m * (SS * HH) + (size_t)t * HH + u] = hv;
  }
}

__global__ __launch_bounds__(512) void k_dec_step(
    const _Float16* __restrict__ W, const float* __restrict__ bias,
    const _Float16* __restrict__ hin, _Float16* __restrict__ hout,
    float* __restrict__ cbuf, const _Float16* __restrict__ outW,
    const float* __restrict__ oB, const float* __restrict__ x,
    float* __restrict__ recon, float* __restrict__ lossAcc, int s) {
  __shared__ float pl[4][4][2][16][16];   // 32 KB
  __shared__ float red[4][2][16][16];     // 8 KB
  __shared__ float pY[4][2][16][16];      // 8 KB
  __shared__ float redY[2][16][16];       // 2 KB
  int tid = threadIdx.x;
  int lane = tid & 63, w = tid >> 6;
  int n = lane & 15, q = lane >> 4;
  int ut = blockIdx.x & 63, mtb = blockIdx.x >> 6;
  int m0 = mtb << 5, u0 = ut << 4;
  bool doY = (s >= 2) && (ut < 8);  // y_{s-1} = h_{s-1} @ out_W.T, d0 = u0

  floatx4 acc[4][2];
#pragma unroll
  for (int g = 0; g < 4; ++g)
#pragma unroll
    for (int mt = 0; mt < 2; ++mt) acc[g][mt] = (floatx4){0, 0, 0, 0};
  floatx4 accY[2];
  accY[0] = (floatx4){0, 0, 0, 0}; accY[1] = (floatx4){0, 0, 0, 0};

  const _Float16* wr0 = W + (size_t)(0 * HH + u0 + n) * HH + q * 8;
  const _Float16* wr1 = W + (size_t)(1 * HH + u0 + n) * HH + q * 8;
  const _Float16* wr2 = W + (size_t)(2 * HH + u0 + n) * HH + q * 8;
  const _Float16* wr3 = W + (size_t)(3 * HH + u0 + n) * HH + q * 8;
  const _Float16* oro = outW + (size_t)(u0 + n) * HH + q * 8;

  int kh0 = w << 7;
  const _Float16* h0 = hin + (size_t)(m0 + n) * HH + kh0 + q * 8;
  const _Float16* h1 = h0 + (size_t)16 * HH;
#pragma unroll
  for (int kk = 0; kk < 4; ++kk) {
    int ko = kk * 32;
    half8 a0 = *(const half8*)(h0 + ko);
    half8 a1 = *(const half8*)(h1 + ko);
    int wk = kh0 + ko;
    half8 b0 = *(const half8*)(wr0 + wk);
    half8 b1 = *(const half8*)(wr1 + wk);
    half8 b2 = *(const half8*)(wr2 + wk);
    half8 b3 = *(const half8*)(wr3 + wk);
    acc[0][0] = MFMA16(a0, b0, acc[0][0]); acc[0][1] = MFMA16(a1, b0, acc[0][1]);
    acc[1][0] = MFMA16(a0, b1, acc[1][0]); acc[1][1] = MFMA16(a1, b1, acc[1][1]);
    acc[2][0] = MFMA16(a0, b2, acc[2][0]); acc[2][1] = MFMA16(a1, b2, acc[2][1]);
    acc[3][0] = MFMA16(a0, b3, acc[3][0]); acc[3][1] = MFMA16(a1, b3, acc[3][1]);
    if (doY) {
      half8 bY = *(const half8*)(oro + wk);
      accY[0] = MFMA16(a0, bY, accY[0]);
      accY[1] = MFMA16(a1, bY, accY[1]);
    }
  }

  if (w >= 4) {
#pragma unroll
    for (int g = 0; g < 4; ++g)
#pragma unroll
      for (int mt = 0; mt < 2; ++mt)
#pragma unroll
        for (int r = 0; r < 4; ++r)
          pl[w - 4][g][mt][q * 4 + r][n] = acc[g][mt][r];
    if (doY)
#pragma unroll
      for (int mt = 0; mt < 2; ++mt)
#pragma unroll
        for (int r = 0; r < 4; ++r)
          pY[w - 4][mt][q * 4 + r][n] = accY[mt][r];
  }
  __syncthreads();
  if (w < 4) {
#pragma unroll
    for (int g = 0; g < 4; ++g)
#pragma unroll
      for (int mt = 0; mt < 2; ++mt)
#pragma unroll
        for (int r = 0; r < 4; ++r) {
          acc[g][mt][r] += pl[w][g][mt][q * 4 + r][n];
          pl[w][g][mt][q * 4 + r][n] = acc[g][mt][r];
        }
    if (doY)
#pragma unroll
      for (int mt = 0; mt < 2; ++mt)
#pragma unroll
        for (int r = 0; r < 4; ++r) {
          accY[mt][r] += pY[w][mt][q * 4 + r][n];
          pY[w][mt][q * 4 + r][n] = accY[mt][r];
        }
  }
  __syncthreads();
  {
    int base = tid * 4;
    int col = base & 15, row = (base >> 4) & 15, mt = (base >> 8) & 1, g = base >> 9;
    floatx4 sv = *(const floatx4*)&pl[0][g][mt][row][col];
    sv += *(const floatx4*)&pl[1][g][mt][row][col];
    sv += *(const floatx4*)&pl[2][g][mt][row][col];
    sv += *(const floatx4*)&pl[3][g][mt][row][col];
    *(floatx4*)&red[g][mt][row][col] = sv;
  }
  if (doY && tid < 128) {
    int base = tid * 4;
    int col = base & 15, row = (base >> 4) & 15, mt = (base >> 8) & 1;
    floatx4 sv = *(const floatx4*)&pY[0][mt][row][col];
    sv += *(const floatx4*)&pY[1][mt][row][col];
    sv += *(const floatx4*)&pY[2][mt][row][col];
    sv += *(const floatx4*)&pY[3][mt][row][col];
    *(floatx4*)&redY[mt][row][col] = sv;
  }
  __syncthreads();
  {
    int m_l = tid >> 4, u_l = tid & 15;
    int mt = m_l >> 4, row = m_l & 15;
    int u = u0 + u_l, m = m0 + m_l;
    float gi = sigf(red[0][mt][row][u_l] + bias[u]);
    float gf = sigf(red[1][mt][row][u_l] + bias[HH + u]);
    float gg = tanhfast(red[2][mt][row][u_l] + bias[2 * HH + u]);
    float go = sigf(red[3][mt][row][u_l] + bias[3 * HH + u]);
    size_t idx = (size_t)m * HH + u;
    float cv = gf * cbuf[idx] + gi * gg;
    cbuf[idx] = cv;
    float hv = go * tanhfast(cv);
    hout[idx] = (_Float16)hv;
    if (doY) {
      int d = u0 + u_l, ty = s - 2;
      float yv = redY[mt][row][u_l] + oB[d];
      size_t ix = (size_t)m * (SS * DD) + (size_t)ty * DD + d;
      recon[ix] = yv;
      float e = yv - x[ix];
      float ls = e * e;
#pragma unroll
      for (int off = 32; off; off >>= 1) ls += __shfl_xor(ls, off, 64);
      if (lane == 0) atomicAdd(lossAcc, ls);
    }
  }
}

__global__ __launch_bounds__(64) void k_y_final(
    const _Float16* __restrict__ hin, const _Float16* __restrict__ outW,
    const float* __restrict__ oB, const float* __restrict__ x,
    float* __restrict__ recon, float* __restrict__ lossAcc) {
  int lane = threadIdx.x;
  int mt = blockIdx.x >> 3, dt = blockIdx.x & 7;
  int n = lane & 15, q = lane >> 4;
  int m0 = mt << 4, d0 = dt << 4;
  floatx4 acc = {0, 0, 0, 0};
  const _Float16* hrow = hin + (size_t)(m0 + n) * HH;
  const _Float16* orow = outW + (size_t)(d0 + n) * HH;
  for (int kI = 0; kI < 32; ++kI) {
    int k0 = kI * 32 + q * 8;
    acc = MFMA16(*(const half8*)(hrow + k0), *(const half8*)(orow + k0), acc);
  }
  int d = d0 + n;
  float ob = oB[d];
  float ls = 0.0f;
#pragma unroll
  for (int r = 0; r < 4; ++r) {
    int m = m0 + q * 4 + r;
    float yv = acc[r] + ob;
    size_t ix = (size_t)m * (SS * DD) + (size_t)511 * DD + d;
    recon[ix] = yv;
    float e = yv - x[ix];
    ls += e * e;
  }
  for (int off = 32; off; off >>= 1) ls += __shfl_xor(ls, off, 64);
  if (lane == 0) atomicAdd(lossAcc, ls);
}

__global__ void k_finalize(const float* __restrict__ lossAcc, float* __restrict__ lossOut) {
  lossOut[0] = lossAcc[0] * (1.0f / (float)BB);
}

// ---- host -------------------------------------------------------------------

extern "C" void kernel_launch(void* const* d_in, const int* in_sizes, int n_in,
                              void* d_out, int out_size, void* d_ws, size_t ws_size,
                              hipStream_t stream) {
  const float* x    = (const float*)d_in[0];
  const float* eWih = (const float*)d_in[1];
  const float* eWhh = (const float*)d_in[2];
  const float* eBih = (const float*)d_in[3];
  const float* eBhh = (const float*)d_in[4];
  const float* dWih = (const float*)d_in[5];
  const float* dWhh = (const float*)d_in[6];
  const float* dBih = (const float*)d_in[7];
  const float* dBhh = (const float*)d_in[8];
  const float* oW   = (const float*)d_in[9];
  const float* oB   = (const float*)d_in[10];

  float* out = (float*)d_out;
  float* recon = out;                                   // (B,S,D)
  float* encOut = out + (size_t)BB * SS * DD;           // (B,S,H)
  float* lossOut = out + (size_t)BB * SS * DD + (size_t)BB * SS * HH;  // scalar

  char* p = (char*)d_ws;
  auto alloc = [&](size_t bytes) {
    char* r = p;
    p += (bytes + 255) & ~(size_t)255;
    return r;
  };
  _Float16* encW   = (_Float16*)alloc((size_t)G4 * KENC * 2);  // [Wih|Whh] fp16
  _Float16* decW1  = (_Float16*)alloc((size_t)G4 * HH * 2);
  _Float16* decW2  = (_Float16*)alloc((size_t)G4 * HH * 2);
  _Float16* outW16 = (_Float16*)alloc((size_t)DD * HH * 2);
  float* encB  = (float*)alloc((size_t)G4 * 4);
  float* decB1 = (float*)alloc((size_t)G4 * 4);
  float* decB2 = (float*)alloc((size_t)G4 * 4);
  _Float16* hA = (_Float16*)alloc((size_t)BB * HH * 2);
  _Float16* hB = (_Float16*)alloc((size_t)BB * HH * 2);
  float* cbuf = (float*)alloc((size_t)BB * HH * 4);
  float* lossAcc = (float*)alloc(256);
  (void)in_sizes; (void)n_in; (void)out_size; (void)ws_size;

  k_prep_encw<<<G4, 256, 0, stream>>>(eWih, eWhh, encW);
  k_prep_simple<<<2048, 256, 0, stream>>>(dWih, dWhh, oW, eBih, eBhh, dBih, dBhh, oB,
                                          decW1, outW16, encB, decB1, decB2, hA, cbuf, lossAcc);
  k_prep_decw2<<<G4 * 4, 256, 0, stream>>>(dWih, dWhh, oW, decW2);

  _Float16* hin = hA;
  _Float16* hout = hB;
  for (int t = 0; t < SS; ++t) {
    k_enc_step<<<256, 512, 0, stream>>>(x, encW, encB, hin, hout, cbuf, encOut, t);
    _Float16* tmp = hin; hin = hout; hout = tmp;
  }
  for (int s = 1; s <= SS; ++s) {
    const _Float16* W = (s == 1) ? decW1 : decW2;
    const float* bias = (s == 1) ? decB1 : decB2;
    k_dec_step<<<256, 512, 0, stream>>>(W, bias, hin, hout, cbuf, outW16, oB, x,
                                        recon, lossAcc, s);
    _Float16* tmp = hin; hin = hout; hout = tmp;
  }
  k_y_final<<<64, 64, 0, stream>>>(hin, outW16, oB, x, recon, lossAcc);
  k_finalize<<<1, 1, 0, stream>>>(lossAcc, lossOut);
}